// Round 3
// baseline (446.421 us; speedup 1.0000x reference)
//
#include <hip/hip_runtime.h>

typedef __attribute__((ext_vector_type(8))) short short8;
typedef __attribute__((ext_vector_type(4))) float f32x4;
typedef unsigned short u16;
typedef unsigned int u32;

#define FENCE() asm volatile("" ::: "memory")

__device__ __forceinline__ void gld_lds16(const void* g, void* l) {
  __builtin_amdgcn_global_load_lds((const __attribute__((address_space(1))) void*)g,
                                   (__attribute__((address_space(3))) void*)l,
                                   16, 0, 0);
}

__device__ __forceinline__ u16 f2b(float x) {
  union { float f; u32 u; } v; v.f = x;
  u32 u = v.u;
  return (u16)((u + 0x7FFFu + ((u >> 16) & 1u)) >> 16);
}
__device__ __forceinline__ float b2f(u16 x) {
  union { u32 u; float f; } v; v.u = ((u32)x) << 16; return v.f;
}
__device__ __forceinline__ u32 pack_pair(float lo, float hi) {
  return (u32)f2b(lo) | ((u32)f2b(hi) << 16);
}

// ==================== merged pre-kernel ====================
// blocks [0,8192): transpose+cast x -> xTz (padded frames)
// blocks [8192,8960): Wcomb[kk][j][ci] = sum_co (Wg[co][j]*s1[co]) * Wd[co][ci][kk]  (bf16-rounded inputs, fp32 acc)
// blocks [8960,9728): Wup[kk][co][ci] cast
// block 9728: c0/tWg
// blocks [9729,10049): zero pad frames of outz/xTz
__global__ __launch_bounds__(256) void k_pre(const float* __restrict__ x,
                                             const float* __restrict__ Wd, const float* __restrict__ Wg,
                                             const float* __restrict__ Wu,
                                             const float* __restrict__ s1, const float* __restrict__ t1,
                                             const float* __restrict__ bg,
                                             u16* __restrict__ xTz, u16* __restrict__ outz,
                                             u16* __restrict__ Wup, u16* __restrict__ Wcomb,
                                             float* __restrict__ c0, float* __restrict__ tWg) {
  __shared__ u16 tile[64][72];
  int blk = blockIdx.x;
  int tid = threadIdx.x;
  if (blk < 8192) {
    int tl = blk >> 4;
    int sub = blk & 15;
    int ci0 = (sub >> 2) << 6;
    int p0 = (sub & 3) << 6;
    int i = tid >> 2;
    int ch = tid & 3;
    const float* gsrc = x + (size_t)tl * 65536 + (ci0 + i) * 256 + p0 + ch * 16;
    __align__(16) u16 cv[16];
#pragma unroll
    for (int v4 = 0; v4 < 4; ++v4) {
      float4 f = *(const float4*)(gsrc + v4 * 4);
      cv[v4 * 4 + 0] = f2b(f.x);
      cv[v4 * 4 + 1] = f2b(f.y);
      cv[v4 * 4 + 2] = f2b(f.z);
      cv[v4 * 4 + 3] = f2b(f.w);
    }
    *(uint4*)&tile[i][ch * 16] = *(const uint4*)&cv[0];
    *(uint4*)&tile[i][ch * 16 + 8] = *(const uint4*)&cv[8];
    __syncthreads();
    __align__(16) u16 tmp[16];
#pragma unroll
    for (int cc = 0; cc < 16; ++cc) tmp[cc] = tile[ch * 16 + cc][i];
    int fi = (tl >> 7) * 129 + (tl & 127) + 1;
    u16* gdst = xTz + (size_t)fi * 65536 + (p0 + i) * 256 + ci0 + ch * 16;
    *(uint4*)(gdst) = *(const uint4*)&tmp[0];
    *(uint4*)(gdst + 8) = *(const uint4*)&tmp[8];
    return;
  }
  if (blk < 8960) {  // direct Wcomb: sum_co (Wg[co][j]*s1[co]) * Wd[co][ci][kk]
    int r = blk - 8192;
    int kk = r >> 8;
    int ci = r & 255;
    int j = tid;
    float a = 0.f;
    for (int co = 0; co < 256; ++co) {
      float wv = b2f(f2b(Wg[co * 256 + j] * s1[co]));
      float dv = b2f(f2b(Wd[(u32)co * 768 + (u32)ci * 3 + kk]));
      a = fmaf(wv, dv, a);
    }
    Wcomb[(size_t)kk * 65536 + (size_t)j * 256 + ci] = f2b(a);
    return;
  }
  if (blk < 9728) {  // Wup cast
    int id = (blk - 8960) * 256 + tid;
    int kk = id >> 16;
    int rem = id & 65535;
    int a = rem >> 8, b = rem & 255;
    Wup[id] = f2b(Wu[(u32)a * 768 + (u32)b * 3 + kk]);
    return;
  }
  if (blk == 9728) {  // c0[j] = t1 @ Wg[:,j] + bg[j]
    int j = tid;
    float a = 0.f;
    for (int co = 0; co < 256; ++co) a += t1[co] * Wg[co * 256 + j];
    tWg[j] = a;
    c0[j] = a + bg[j];
    return;
  }
  // zero pad frames
  int gid = (blk - 9729) * 256 + tid;
  int i = gid * 8;
  int buf = (i >= 327680) ? 1 : 0;
  int wi = i - buf * 327680;
  int f = wi >> 16;
  int off = wi & 65535;
  u16* dst = (buf ? xTz : outz) + (size_t)f * 129 * 65536 + off;
  *(uint4*)dst = make_uint4(0u, 0u, 0u, 0u);
}

// ---------------- output store helpers ----------------
__device__ __forceinline__ void store_pairs(u16* base, int row0, int stride, int colb,
                                            const float v[4], bool ev) {
  float pv[4];
#pragma unroll
  for (int r = 0; r < 4; ++r) pv[r] = __shfl_xor(v[r], 1, 64);
  u32 wd0 = ev ? pack_pair(v[0], pv[0]) : pack_pair(pv[0], v[0]);
  u32 wd1 = ev ? pack_pair(v[1], pv[1]) : pack_pair(pv[1], v[1]);
  u32 wd2 = ev ? pack_pair(v[2], pv[2]) : pack_pair(pv[2], v[2]);
  u32 wd3 = ev ? pack_pair(v[3], pv[3]) : pack_pair(pv[3], v[3]);
  u32 wa = ev ? wd0 : wd2;
  u32 wb = ev ? wd1 : wd3;
  int rs = ev ? 0 : 2;
  *(u32*)(base + (size_t)(row0 + rs) * stride + colb) = wa;
  *(u32*)(base + (size_t)(row0 + rs + 1) * stride + colb) = wb;
}

__device__ __forceinline__ void store_pairs_f32(float* base, int row0, int stride, int colb,
                                                const float v[4], bool ev) {
  float pv[4];
#pragma unroll
  for (int r = 0; r < 4; ++r) pv[r] = __shfl_xor(v[r], 1, 64);
  float2 wa, wb;
  if (ev) { wa = make_float2(v[0], pv[0]); wb = make_float2(v[1], pv[1]); }
  else    { wa = make_float2(pv[2], v[2]); wb = make_float2(pv[3], v[3]); }
  int rs = ev ? 0 : 2;
  *(float2*)(base + (size_t)(row0 + rs) * stride + colb) = wa;
  *(float2*)(base + (size_t)(row0 + rs + 1) * stride + colb) = wb;
}

// ================= 256x256 GEMM core, 2-barrier/K-tile counted-vmcnt schedule =================
// C[256x256] = sum over 12 K-tiles (BK=64) of A[256xK] * B[256xK]^T
// LDS: [dbuf 2][half 2][128 rows][64 k] bf16 per operand, XOR-swizzled via pre-swizzled
// global source (linear gld_lds dest). Stage stream per tile kt:
//   seg1 stages A(kt+1) -> other buffer; seg2 stages B(kt+2) -> current buffer's B region
//   (all B reads of tile kt retired before barrier B1).
// vmcnt(4) at tile end drains A(kt+1)+B(kt+1), leaves B(kt+2) in flight.

__device__ __forceinline__ void stage_half(const u16* __restrict__ op, int tau, int half,
                                           u16* sdst, int g0, int wuni) {
  const int toff = ((tau >> 2) << 16) + ((tau & 3) << 6);
  const u16* src = op + toff + (half << 15) + g0;
  u16* dst = sdst + ((tau & 1) << 14) + (half << 13) + wuni;
  gld_lds16(src, dst);
  gld_lds16(src + 16384, dst + 4096);
}

__device__ __forceinline__ void gemm256_core(const u16* __restrict__ Ab, const u16* __restrict__ Bb,
                                             u16* sA, u16* sB, int tid, f32x4 (&acc)[8][4]) {
  const int lane = tid & 63;
  const int w = tid >> 6;
  const int wr = w >> 2;        // 0..1
  const int wc = w & 3;         // 0..3
  const int m16 = lane & 15;
  const int xorm = (lane & 7) << 4;       // swizzle mask (bytes)
  const int q16b = (lane >> 4) << 4;      // k-quarter byte offset
  const int koffe0 = (q16b ^ xorm) >> 1;         // elems
  const int koffe1 = ((64 + q16b) ^ xorm) >> 1;  // elems
  const int srow = tid >> 3;
  const int scol = ((tid & 7) ^ (srow & 7)) << 3;
  const int g0 = srow * 256 + scol;
  const int wuni = w << 9;

#pragma unroll
  for (int i = 0; i < 8; ++i)
#pragma unroll
    for (int j = 0; j < 4; ++j) acc[i][j] = (f32x4){0.f, 0.f, 0.f, 0.f};

  // prologue: A(0), B(0), B(1) = 12 gld; wait A(0)+B(0)
  stage_half(Ab, 0, 0, sA, g0, wuni);
  stage_half(Ab, 0, 1, sA, g0, wuni);
  stage_half(Bb, 0, 0, sB, g0, wuni);
  stage_half(Bb, 0, 1, sB, g0, wuni);
  stage_half(Bb, 1, 0, sB, g0, wuni);
  stage_half(Bb, 1, 1, sB, g0, wuni);
  asm volatile("s_waitcnt vmcnt(4)" ::: "memory");
  __builtin_amdgcn_s_barrier();
  FENCE();

  short8 a0[4], a1[4], bf0[4], bf1[4];
#pragma unroll 2
  for (int kt = 0; kt < 12; ++kt) {
    const u16* aH = sA + (kt & 1) * 16384 + wr * 8192;
    const u16* bH = sB + (kt & 1) * 16384 + (wc >> 1) * 8192;
    const int bR0 = (wc & 1) << 6;
    // ---- segment 1: C row-quad0 (rows 0..63 of wave block), k0 then k1 ----
#pragma unroll
    for (int m = 0; m < 4; ++m) a0[m] = *(const short8*)(aH + (m * 16 + m16) * 64 + koffe0);
#pragma unroll
    for (int n = 0; n < 4; ++n) bf0[n] = *(const short8*)(bH + (bR0 + n * 16 + m16) * 64 + koffe0);
    if (kt < 11) stage_half(Ab, kt + 1, 0, sA, g0, wuni);
    __builtin_amdgcn_s_setprio(1);
#pragma unroll
    for (int m = 0; m < 4; ++m)
#pragma unroll
      for (int n = 0; n < 4; ++n)
        acc[m][n] = __builtin_amdgcn_mfma_f32_16x16x32_bf16(a0[m], bf0[n], acc[m][n], 0, 0, 0);
    __builtin_amdgcn_s_setprio(0);
#pragma unroll
    for (int m = 0; m < 4; ++m) a1[m] = *(const short8*)(aH + (m * 16 + m16) * 64 + koffe1);
#pragma unroll
    for (int n = 0; n < 4; ++n) bf1[n] = *(const short8*)(bH + (bR0 + n * 16 + m16) * 64 + koffe1);
    if (kt < 11) stage_half(Ab, kt + 1, 1, sA, g0, wuni);
    __builtin_amdgcn_s_setprio(1);
#pragma unroll
    for (int m = 0; m < 4; ++m)
#pragma unroll
      for (int n = 0; n < 4; ++n)
        acc[m][n] = __builtin_amdgcn_mfma_f32_16x16x32_bf16(a1[m], bf1[n], acc[m][n], 0, 0, 0);
    __builtin_amdgcn_s_setprio(0);
    asm volatile("s_waitcnt lgkmcnt(0)" ::: "memory");  // all B reads of tile kt retired
    FENCE();
    __builtin_amdgcn_s_barrier();   // B1: B region of current buffer now free
    FENCE();
    // ---- segment 2: C row-quad1 (rows 64..127), reuse bf0/bf1 ----
#pragma unroll
    for (int m = 0; m < 4; ++m) a0[m] = *(const short8*)(aH + ((64 + m * 16) + m16) * 64 + koffe0);
    if (kt < 10) stage_half(Bb, kt + 2, 0, sB, g0, wuni);
    __builtin_amdgcn_s_setprio(1);
#pragma unroll
    for (int m = 0; m < 4; ++m)
#pragma unroll
      for (int n = 0; n < 4; ++n)
        acc[4 + m][n] = __builtin_amdgcn_mfma_f32_16x16x32_bf16(a0[m], bf0[n], acc[4 + m][n], 0, 0, 0);
    __builtin_amdgcn_s_setprio(0);
#pragma unroll
    for (int m = 0; m < 4; ++m) a1[m] = *(const short8*)(aH + ((64 + m * 16) + m16) * 64 + koffe1);
    if (kt < 10) stage_half(Bb, kt + 2, 1, sB, g0, wuni);
    __builtin_amdgcn_s_setprio(1);
#pragma unroll
    for (int m = 0; m < 4; ++m)
#pragma unroll
      for (int n = 0; n < 4; ++n)
        acc[4 + m][n] = __builtin_amdgcn_mfma_f32_16x16x32_bf16(a1[m], bf1[n], acc[4 + m][n], 0, 0, 0);
    __builtin_amdgcn_s_setprio(0);
    asm volatile("s_waitcnt lgkmcnt(0)" ::: "memory");
    if (kt < 10) asm volatile("s_waitcnt vmcnt(4)" ::: "memory");
    else         asm volatile("s_waitcnt vmcnt(0)" ::: "memory");
    FENCE();
    __builtin_amdgcn_s_barrier();   // B2: next tile's A+B guaranteed landed (all waves)
    FENCE();
  }
}

// ---- G12: out_pre[bt][p][j] = sum_kk xTz_frames @ Wcomb_kk^T + c0 ; edge dump p<4 ----
__global__ __launch_bounds__(512, 2) void k_g12(const u16* __restrict__ xTz, const u16* __restrict__ Wcomb,
                                                const float* __restrict__ c0, const float* __restrict__ tWg,
                                                u16* __restrict__ outz, float* __restrict__ edge) {
  __shared__ u16 sA[32768];
  __shared__ u16 sB[32768];
  int bsw = (int)blockIdx.x;
  int bt = (bsw & 7) * 64 + (bsw >> 3);   // XCD swizzle (512 = 8*64)
  int b = bt >> 7, t = bt & 127;
  int tid = threadIdx.x;
  const u16* Ab = xTz + (size_t)(b * 129 + t) * 65536;
  const u16* Bb = Wcomb;
  f32x4 acc[8][4];
  gemm256_core(Ab, Bb, sA, sB, tid, acc);

  int lane = tid & 63, w = tid >> 6, wr = w >> 2, wc = w & 3;
  int q = lane >> 4, cc16 = lane & 15;
  bool ev = (lane & 1) == 0;
  float c0v[4], tWgv[4];
#pragma unroll
  for (int ni = 0; ni < 4; ++ni) {
    int j = wc * 64 + ni * 16 + cc16;
    c0v[ni] = c0[j];
    tWgv[ni] = tWg[j];
  }
  u16* obase = outz + (size_t)(b * 129 + t + 1) * 65536;
#pragma unroll
  for (int mi = 0; mi < 8; ++mi) {
    int row0 = wr * 128 + mi * 16 + q * 4;
#pragma unroll
    for (int ni = 0; ni < 4; ++ni) {
      float v[4];
#pragma unroll
      for (int r = 0; r < 4; ++r) v[r] = acc[mi][ni][r] + c0v[ni];
      store_pairs(obase, row0, 256, wc * 64 + ni * 16 + (cc16 & ~1), v, ev);
    }
  }
  if (wr == 0 && q == 0) {
    float* eb = edge + (size_t)bt * 1024;
#pragma unroll
    for (int ni = 0; ni < 4; ++ni) {
      float vE[4];
#pragma unroll
      for (int r = 0; r < 4; ++r) vE[r] = acc[0][ni][r] + tWgv[ni];
      store_pairs_f32(eb, 0, 256, wc * 64 + ni * 16 + (cc16 & ~1), vE, ev);
    }
  }
}

// ---- fixup: overwrite p<4 nodes with GCN aggregation (closed-form dinv) ----
__device__ __forceinline__ float dinv0(int t) {
  if (t == 0) return 0.44721359549995793f;   // 1/sqrt(5)
  if (t == 127) return 0.7071067811865476f;  // 1/sqrt(2)
  return 0.4082482904638631f;                // 1/sqrt(6)
}
__global__ __launch_bounds__(256) void k_fix(const float* __restrict__ edge, const float* __restrict__ bg,
                                             u16* __restrict__ outz) {
  int bt = blockIdx.x;
  int b = bt >> 7;
  int t = bt & 127;
  int j = threadIdx.x;
  const float ISQ2 = 0.7071067811865476f;
  float bgv = bg[j];
  float e_t = edge[(size_t)bt * 1024 + j];
  float At = dinv0(t);
  float o0 = bgv + At * At * e_t;
  if (t <= 126) {
    float At1 = dinv0(t + 1);
    const float* en = edge + (size_t)(bt + 1) * 1024;
    float s = At1 * en[j] + ISQ2 * (en[256 + j] + en[512 + j] + en[768 + j]);
    o0 += At * s;
  }
  float em1 = 0.f, Atm1 = 0.f;
  if (t >= 1) {
    Atm1 = dinv0(t - 1);
    em1 = edge[(size_t)(bt - 1) * 1024 + j];
    o0 += At * Atm1 * em1;
  }
  u16* ob = outz + (size_t)(b * 129 + t + 1) * 65536;
  ob[j] = f2b(o0);
#pragma unroll
  for (int k = 1; k <= 3; ++k) {
    float m = edge[(size_t)bt * 1024 + k * 256 + j];
    float ok = (t == 0) ? (bgv + m) : (bgv + 0.5f * m + ISQ2 * Atm1 * em1);
    ob[k * 256 + j] = f2b(ok);
  }
}

// ---- G3: y[bt][co][p] = (Wup_kk @ outz_frames^T)*s2 + t2, fp32 out ----
__global__ __launch_bounds__(512, 2) void k_g3(const u16* __restrict__ outz, const u16* __restrict__ Wup,
                                               const float* __restrict__ s2, const float* __restrict__ t2,
                                               float* __restrict__ y) {
  __shared__ u16 sA[32768];
  __shared__ u16 sB[32768];
  int bsw = (int)blockIdx.x;
  int bt = (bsw & 7) * 64 + (bsw >> 3);
  int b = bt >> 7, t = bt & 127;
  int tid = threadIdx.x;
  const u16* Ab = Wup;
  const u16* Bb = outz + (size_t)(b * 129 + t) * 65536;
  f32x4 acc[8][4];
  gemm256_core(Ab, Bb, sA, sB, tid, acc);

  int lane = tid & 63, w = tid >> 6, wr = w >> 2, wc = w & 3;
  int q = lane >> 4, cc16 = lane & 15;
  bool ev = (lane & 1) == 0;
  float* ybase = y + (size_t)bt * 65536;
#pragma unroll
  for (int mi = 0; mi < 8; ++mi) {
    int rl = wr * 128 + mi * 16 + q * 4;
    float4 s4 = *(const float4*)(s2 + rl);
    float4 t4 = *(const float4*)(t2 + rl);
#pragma unroll
    for (int ni = 0; ni < 4; ++ni) {
      float v[4];
      v[0] = acc[mi][ni][0] * s4.x + t4.x;
      v[1] = acc[mi][ni][1] * s4.y + t4.y;
      v[2] = acc[mi][ni][2] * s4.z + t4.z;
      v[3] = acc[mi][ni][3] * s4.w + t4.w;
      store_pairs_f32(ybase, rl, 256, wc * 64 + ni * 16 + (cc16 & ~1), v, ev);
    }
  }
}

extern "C" void kernel_launch(void* const* d_in, const int* in_sizes, int n_in,
                              void* d_out, int out_size, void* d_ws, size_t ws_size,
                              hipStream_t stream) {
  (void)in_sizes; (void)n_in; (void)out_size; (void)ws_size;
  const float* x  = (const float*)d_in[0];
  const float* Wd = (const float*)d_in[2];
  const float* s1 = (const float*)d_in[3];
  const float* t1 = (const float*)d_in[4];
  const float* Wg = (const float*)d_in[5];
  const float* bg = (const float*)d_in[6];
  const float* Wu = (const float*)d_in[7];
  const float* s2 = (const float*)d_in[8];
  const float* t2 = (const float*)d_in[9];
  float* y = (float*)d_out;
  char* ws = (char*)d_ws;
  // padded layout: 517 frames (4*129+1), frames b*129 are shared zero pads
  u16*   outz  = (u16*)(ws);                    // 67,764,224 B
  u16*   xTz   = (u16*)(ws + 67764224);         // 67,764,224 B
  u16*   Wup   = (u16*)(ws + 136052736);        // 384 KiB
  u16*   Wcomb = (u16*)(ws + 136445952);        // 384 KiB
  float* c0    = (float*)(ws + 136839168);      // 1 KiB
  float* tWg   = (float*)(ws + 136840192);      // 1 KiB
  float* edge  = (float*)d_out;                 // scratch in d_out, overwritten by k_g3

  k_pre<<<dim3(10049), dim3(256), 0, stream>>>(x, Wd, Wg, Wu, s1, t1, bg, xTz, outz, Wup, Wcomb, c0, tWg);
  k_g12<<<dim3(512), dim3(512), 0, stream>>>(xTz, Wcomb, c0, tWg, outz, edge);
  k_fix<<<dim3(512), dim3(256), 0, stream>>>(edge, bg, outz);
  k_g3<<<dim3(512), dim3(512), 0, stream>>>(outz, Wup, s2, t2, y);
}

// Round 4
// 405.874 us; speedup vs baseline: 1.0999x; 1.0999x over previous
//
#include <hip/hip_runtime.h>

typedef __attribute__((ext_vector_type(8))) short short8;
typedef __attribute__((ext_vector_type(4))) float f32x4;
typedef unsigned short u16;
typedef unsigned int u32;

#define FENCE() asm volatile("" ::: "memory")

__device__ __forceinline__ void gld_lds16(const void* g, void* l) {
  __builtin_amdgcn_global_load_lds((const __attribute__((address_space(1))) void*)g,
                                   (__attribute__((address_space(3))) void*)l,
                                   16, 0, 0);
}

__device__ __forceinline__ u16 f2b(float x) {
  union { float f; u32 u; } v; v.f = x;
  u32 u = v.u;
  return (u16)((u + 0x7FFFu + ((u >> 16) & 1u)) >> 16);
}
__device__ __forceinline__ float b2f(u16 x) {
  union { u32 u; float f; } v; v.u = ((u32)x) << 16; return v.f;
}
__device__ __forceinline__ u32 pack_pair(float lo, float hi) {
  return (u32)f2b(lo) | ((u32)f2b(hi) << 16);
}

// ==================== merged pre-kernel ====================
// Dispatch order puts the SERIAL-LOOP blocks first so their latency hides
// under the 8192-block transpose bulk (round-3 post-mortem: they formed a
// 60-80us tail when dispatched last).
// blocks [0,768):      Wcomb[kk][j][ci] = sum_co (Wg[co][j]*s1[co]) * Wd[co][ci][kk]
// block  768:          c0/tWg
// blocks [769,1537):   Wup[kk][co][ci] cast
// blocks [1537,1857):  zero pad frames of outz/xTz
// blocks [1857,10049): transpose+cast x -> xTz (padded frames)
__global__ __launch_bounds__(256) void k_pre(const float* __restrict__ x,
                                             const float* __restrict__ Wd, const float* __restrict__ Wg,
                                             const float* __restrict__ Wu,
                                             const float* __restrict__ s1, const float* __restrict__ t1,
                                             const float* __restrict__ bg,
                                             u16* __restrict__ xTz, u16* __restrict__ outz,
                                             u16* __restrict__ Wup, u16* __restrict__ Wcomb,
                                             float* __restrict__ c0, float* __restrict__ tWg) {
  __shared__ u16 tile[64][72];
  int blk = blockIdx.x;
  int tid = threadIdx.x;
  if (blk < 768) {  // direct Wcomb, 4-way unrolled independent partials
    int kk = blk >> 8;
    int ci = blk & 255;
    int j = tid;
    float a0 = 0.f, a1 = 0.f, a2 = 0.f, a3 = 0.f;
    for (int co = 0; co < 256; co += 4) {
      float w0 = b2f(f2b(Wg[(co + 0) * 256 + j] * s1[co + 0]));
      float w1 = b2f(f2b(Wg[(co + 1) * 256 + j] * s1[co + 1]));
      float w2 = b2f(f2b(Wg[(co + 2) * 256 + j] * s1[co + 2]));
      float w3 = b2f(f2b(Wg[(co + 3) * 256 + j] * s1[co + 3]));
      float d0 = b2f(f2b(Wd[(u32)(co + 0) * 768 + (u32)ci * 3 + kk]));
      float d1 = b2f(f2b(Wd[(u32)(co + 1) * 768 + (u32)ci * 3 + kk]));
      float d2 = b2f(f2b(Wd[(u32)(co + 2) * 768 + (u32)ci * 3 + kk]));
      float d3 = b2f(f2b(Wd[(u32)(co + 3) * 768 + (u32)ci * 3 + kk]));
      a0 = fmaf(w0, d0, a0);
      a1 = fmaf(w1, d1, a1);
      a2 = fmaf(w2, d2, a2);
      a3 = fmaf(w3, d3, a3);
    }
    Wcomb[(size_t)kk * 65536 + (size_t)j * 256 + ci] = f2b((a0 + a1) + (a2 + a3));
    return;
  }
  if (blk == 768) {  // c0[j] = t1 @ Wg[:,j] + bg[j], 4-way unrolled
    int j = tid;
    float a0 = 0.f, a1 = 0.f, a2 = 0.f, a3 = 0.f;
    for (int co = 0; co < 256; co += 4) {
      a0 = fmaf(t1[co + 0], Wg[(co + 0) * 256 + j], a0);
      a1 = fmaf(t1[co + 1], Wg[(co + 1) * 256 + j], a1);
      a2 = fmaf(t1[co + 2], Wg[(co + 2) * 256 + j], a2);
      a3 = fmaf(t1[co + 3], Wg[(co + 3) * 256 + j], a3);
    }
    float a = (a0 + a1) + (a2 + a3);
    tWg[j] = a;
    c0[j] = a + bg[j];
    return;
  }
  if (blk < 1537) {  // Wup cast
    int id = (blk - 769) * 256 + tid;
    int kk = id >> 16;
    int rem = id & 65535;
    int a = rem >> 8, b = rem & 255;
    Wup[id] = f2b(Wu[(u32)a * 768 + (u32)b * 3 + kk]);
    return;
  }
  if (blk < 1857) {  // zero pad frames
    int gid = (blk - 1537) * 256 + tid;
    int i = gid * 8;
    int buf = (i >= 327680) ? 1 : 0;
    int wi = i - buf * 327680;
    int f = wi >> 16;
    int off = wi & 65535;
    u16* dst = (buf ? xTz : outz) + (size_t)f * 129 * 65536 + off;
    *(uint4*)dst = make_uint4(0u, 0u, 0u, 0u);
    return;
  }
  // transpose+cast
  int tblk = blk - 1857;
  int tl = tblk >> 4;
  int sub = tblk & 15;
  int ci0 = (sub >> 2) << 6;
  int p0 = (sub & 3) << 6;
  int i = tid >> 2;
  int ch = tid & 3;
  const float* gsrc = x + (size_t)tl * 65536 + (ci0 + i) * 256 + p0 + ch * 16;
  __align__(16) u16 cv[16];
#pragma unroll
  for (int v4 = 0; v4 < 4; ++v4) {
    float4 f = *(const float4*)(gsrc + v4 * 4);
    cv[v4 * 4 + 0] = f2b(f.x);
    cv[v4 * 4 + 1] = f2b(f.y);
    cv[v4 * 4 + 2] = f2b(f.z);
    cv[v4 * 4 + 3] = f2b(f.w);
  }
  *(uint4*)&tile[i][ch * 16] = *(const uint4*)&cv[0];
  *(uint4*)&tile[i][ch * 16 + 8] = *(const uint4*)&cv[8];
  __syncthreads();
  __align__(16) u16 tmp[16];
#pragma unroll
  for (int cc = 0; cc < 16; ++cc) tmp[cc] = tile[ch * 16 + cc][i];
  int fi = (tl >> 7) * 129 + (tl & 127) + 1;
  u16* gdst = xTz + (size_t)fi * 65536 + (p0 + i) * 256 + ci0 + ch * 16;
  *(uint4*)(gdst) = *(const uint4*)&tmp[0];
  *(uint4*)(gdst + 8) = *(const uint4*)&tmp[8];
}

// ---------------- output store helpers ----------------
__device__ __forceinline__ void store_pairs(u16* base, int row0, int stride, int colb,
                                            const float v[4], bool ev) {
  float pv[4];
#pragma unroll
  for (int r = 0; r < 4; ++r) pv[r] = __shfl_xor(v[r], 1, 64);
  u32 wd0 = ev ? pack_pair(v[0], pv[0]) : pack_pair(pv[0], v[0]);
  u32 wd1 = ev ? pack_pair(v[1], pv[1]) : pack_pair(pv[1], v[1]);
  u32 wd2 = ev ? pack_pair(v[2], pv[2]) : pack_pair(pv[2], v[2]);
  u32 wd3 = ev ? pack_pair(v[3], pv[3]) : pack_pair(pv[3], v[3]);
  u32 wa = ev ? wd0 : wd2;
  u32 wb = ev ? wd1 : wd3;
  int rs = ev ? 0 : 2;
  *(u32*)(base + (size_t)(row0 + rs) * stride + colb) = wa;
  *(u32*)(base + (size_t)(row0 + rs + 1) * stride + colb) = wb;
}

__device__ __forceinline__ void store_pairs_f32(float* base, int row0, int stride, int colb,
                                                const float v[4], bool ev) {
  float pv[4];
#pragma unroll
  for (int r = 0; r < 4; ++r) pv[r] = __shfl_xor(v[r], 1, 64);
  float2 wa, wb;
  if (ev) { wa = make_float2(v[0], pv[0]); wb = make_float2(v[1], pv[1]); }
  else    { wa = make_float2(pv[2], v[2]); wb = make_float2(pv[3], v[3]); }
  int rs = ev ? 0 : 2;
  *(float2*)(base + (size_t)(row0 + rs) * stride + colb) = wa;
  *(float2*)(base + (size_t)(row0 + rs + 1) * stride + colb) = wb;
}

// ================= 256x256 8-phase GEMM core (round-1 verified: 78.9us) =================
// C[256x256] = sum over 12 K-tiles (BK=64) of A[256xK] * B[256xK]^T
// LDS: [dbuf 2][half 2][128 rows][64 k] bf16, XOR-swizzled (byte ^= (row&7)<<4),
// achieved by pre-swizzling the GLOBAL source address (LDS dest stays linear).

__device__ __forceinline__ void stage_part(int s, const u16* Ab, const u16* Bb,
                                           u16* sA, u16* sB, int wuni, int g0) {
  if (s >= 48) return;
  const int tau = s >> 2;
  const int pt = s & 3;              // 0=B0,1=B1,2=A0,3=A1
  const int toff = ((tau >> 2) << 16) + ((tau & 3) << 6);
  const int half = pt & 1;
  const u16* src = ((pt & 2) ? Ab : Bb) + toff + (half << 15) + g0;
  u16* dst = ((pt & 2) ? sA : sB) + ((tau & 1) << 14) + (half << 13) + wuni;
  gld_lds16(src, dst);
  gld_lds16(src + 16384, dst + 4096);
}

template<int QUAD, int NH>
__device__ __forceinline__ void mfma_quad(f32x4 (&acc)[8][4], const short8 (&af)[2][4],
                                          const short8 (&bf)[2][2][2]) {
#pragma unroll
  for (int k = 0; k < 2; ++k)
#pragma unroll
    for (int m = 0; m < 4; ++m)
#pragma unroll
      for (int nj = 0; nj < 2; ++nj)
        acc[QUAD * 4 + m][NH * 2 + nj] = __builtin_amdgcn_mfma_f32_16x16x32_bf16(
            af[k][m], bf[NH][k][nj], acc[QUAD * 4 + m][NH * 2 + nj], 0, 0, 0);
}

__device__ __forceinline__ void gemm256_core(const u16* __restrict__ Ab, const u16* __restrict__ Bb,
                                             u16* sA, u16* sB, int tid, f32x4 (&acc)[8][4]) {
  const int lane = tid & 63;
  const int w = tid >> 6;
  const int wr = w >> 2;        // 0..1
  const int wc = w & 3;         // 0..3
  const int m16 = lane & 15;
  const int xorm = (lane & 7) << 4;       // swizzle mask (bytes)
  const int q16b = (lane >> 4) << 4;      // k-quarter byte offset
  const int koffe0 = ((q16b) ^ xorm) >> 1;        // elems
  const int koffe1 = ((64 + q16b) ^ xorm) >> 1;   // elems
  // staging: thread's global offset (pre-swizzled so linear LDS holds swizzled data)
  const int srow = tid >> 3;                       // 0..63 (j=0)
  const int scol = ((tid & 7) ^ (srow & 7)) << 3;  // 0..56
  const int g0 = srow * 256 + scol;                // j=1 adds 16384
  const int wuni = w << 9;                         // wave-uniform LDS elem base

#pragma unroll
  for (int i = 0; i < 8; ++i)
#pragma unroll
    for (int j = 0; j < 4; ++j) acc[i][j] = (f32x4){0.f, 0.f, 0.f, 0.f};

  // prologue: stage stream parts 0..6 (tile0 all, tile1 B0,B1,A0)
#pragma unroll
  for (int s = 0; s < 7; ++s) stage_part(s, Ab, Bb, sA, sB, wuni, g0);
  asm volatile("s_waitcnt vmcnt(6)" ::: "memory");
  __builtin_amdgcn_s_barrier();
  FENCE();

  short8 af[2][4];
  short8 bf[2][2][2];
#pragma unroll 2
  for (int kt = 0; kt < 12; ++kt) {
    const int cb = kt & 1;
    const u16* aH = sA + cb * 16384 + wr * 8192;
    const u16* bH = sB + cb * 16384 + (wc >> 1) * 8192;
    const int bR0 = (wc & 1) << 6;
    // ---- phase 0: load A-quad0 + all B frags; stage A1(kt+1); MFMA Q(0,0) ----
#pragma unroll
    for (int m = 0; m < 4; ++m) {
      const u16* p = aH + (m * 16 + m16) * 64;
      af[0][m] = *(const short8*)(p + koffe0);
      af[1][m] = *(const short8*)(p + koffe1);
    }
#pragma unroll
    for (int nh = 0; nh < 2; ++nh)
#pragma unroll
      for (int nj = 0; nj < 2; ++nj) {
        const u16* p = bH + (bR0 + (nh * 2 + nj) * 16 + m16) * 64;
        bf[nh][0][nj] = *(const short8*)(p + koffe0);
        bf[nh][1][nj] = *(const short8*)(p + koffe1);
      }
    stage_part(4 * kt + 7, Ab, Bb, sA, sB, wuni, g0);
    FENCE();
    __builtin_amdgcn_s_barrier();
    FENCE();
    __builtin_amdgcn_s_setprio(1);
    mfma_quad<0, 0>(acc, af, bf);
    __builtin_amdgcn_s_setprio(0);
    FENCE();
    __builtin_amdgcn_s_barrier();
    FENCE();
    // ---- phase 1: stage B0(kt+2); MFMA Q(0,1) ----
    stage_part(4 * kt + 8, Ab, Bb, sA, sB, wuni, g0);
    FENCE();
    __builtin_amdgcn_s_barrier();
    FENCE();
    __builtin_amdgcn_s_setprio(1);
    mfma_quad<0, 1>(acc, af, bf);
    __builtin_amdgcn_s_setprio(0);
    FENCE();
    __builtin_amdgcn_s_barrier();
    FENCE();
    // ---- phase 2: reload A-quad1; stage B1(kt+2); MFMA Q(1,0) ----
#pragma unroll
    for (int m = 0; m < 4; ++m) {
      const u16* p = aH + (64 + m * 16 + m16) * 64;
      af[0][m] = *(const short8*)(p + koffe0);
      af[1][m] = *(const short8*)(p + koffe1);
    }
    stage_part(4 * kt + 9, Ab, Bb, sA, sB, wuni, g0);
    FENCE();
    __builtin_amdgcn_s_barrier();
    FENCE();
    __builtin_amdgcn_s_setprio(1);
    mfma_quad<1, 0>(acc, af, bf);
    __builtin_amdgcn_s_setprio(0);
    FENCE();
    __builtin_amdgcn_s_barrier();
    FENCE();
    // ---- phase 3: stage A0(kt+2); MFMA Q(1,1); counted vmcnt ----
    stage_part(4 * kt + 10, Ab, Bb, sA, sB, wuni, g0);
    FENCE();
    __builtin_amdgcn_s_barrier();
    FENCE();
    __builtin_amdgcn_s_setprio(1);
    mfma_quad<1, 1>(acc, af, bf);
    __builtin_amdgcn_s_setprio(0);
    if (kt < 10) asm volatile("s_waitcnt vmcnt(6)" ::: "memory");
    else         asm volatile("s_waitcnt vmcnt(0)" ::: "memory");
    __builtin_amdgcn_s_barrier();
    FENCE();
  }
}

// ---- G12: out_pre[bt][p][j] = sum_kk xTz_frames @ Wcomb_kk^T + c0 ; edge dump p<4 ----
__global__ __launch_bounds__(512, 2) void k_g12(const u16* __restrict__ xTz, const u16* __restrict__ Wcomb,
                                                const float* __restrict__ c0, const float* __restrict__ tWg,
                                                u16* __restrict__ outz, float* __restrict__ edge) {
  __shared__ u16 sA[32768];
  __shared__ u16 sB[32768];
  int bsw = (int)blockIdx.x;
  int bt = (bsw & 7) * 64 + (bsw >> 3);   // XCD swizzle (512 = 8*64)
  int b = bt >> 7, t = bt & 127;
  int tid = threadIdx.x;
  const u16* Ab = xTz + (size_t)(b * 129 + t) * 65536;
  const u16* Bb = Wcomb;
  f32x4 acc[8][4];
  gemm256_core(Ab, Bb, sA, sB, tid, acc);

  int lane = tid & 63, w = tid >> 6, wr = w >> 2, wc = w & 3;
  int q = lane >> 4, cc16 = lane & 15;
  bool ev = (lane & 1) == 0;
  float c0v[4], tWgv[4];
#pragma unroll
  for (int ni = 0; ni < 4; ++ni) {
    int j = wc * 64 + ni * 16 + cc16;
    c0v[ni] = c0[j];
    tWgv[ni] = tWg[j];
  }
  u16* obase = outz + (size_t)(b * 129 + t + 1) * 65536;
#pragma unroll
  for (int mi = 0; mi < 8; ++mi) {
    int row0 = wr * 128 + mi * 16 + q * 4;
#pragma unroll
    for (int ni = 0; ni < 4; ++ni) {
      float v[4];
#pragma unroll
      for (int r = 0; r < 4; ++r) v[r] = acc[mi][ni][r] + c0v[ni];
      store_pairs(obase, row0, 256, wc * 64 + ni * 16 + (cc16 & ~1), v, ev);
    }
  }
  if (wr == 0 && q == 0) {
    float* eb = edge + (size_t)bt * 1024;
#pragma unroll
    for (int ni = 0; ni < 4; ++ni) {
      float vE[4];
#pragma unroll
      for (int r = 0; r < 4; ++r) vE[r] = acc[0][ni][r] + tWgv[ni];
      store_pairs_f32(eb, 0, 256, wc * 64 + ni * 16 + (cc16 & ~1), vE, ev);
    }
  }
}

// ---- fixup: overwrite p<4 nodes with GCN aggregation (closed-form dinv) ----
__device__ __forceinline__ float dinv0(int t) {
  if (t == 0) return 0.44721359549995793f;   // 1/sqrt(5)
  if (t == 127) return 0.7071067811865476f;  // 1/sqrt(2)
  return 0.4082482904638631f;                // 1/sqrt(6)
}
__global__ __launch_bounds__(256) void k_fix(const float* __restrict__ edge, const float* __restrict__ bg,
                                             u16* __restrict__ outz) {
  int bt = blockIdx.x;
  int b = bt >> 7;
  int t = bt & 127;
  int j = threadIdx.x;
  const float ISQ2 = 0.7071067811865476f;
  float bgv = bg[j];
  float e_t = edge[(size_t)bt * 1024 + j];
  float At = dinv0(t);
  float o0 = bgv + At * At * e_t;
  if (t <= 126) {
    float At1 = dinv0(t + 1);
    const float* en = edge + (size_t)(bt + 1) * 1024;
    float s = At1 * en[j] + ISQ2 * (en[256 + j] + en[512 + j] + en[768 + j]);
    o0 += At * s;
  }
  float em1 = 0.f, Atm1 = 0.f;
  if (t >= 1) {
    Atm1 = dinv0(t - 1);
    em1 = edge[(size_t)(bt - 1) * 1024 + j];
    o0 += At * Atm1 * em1;
  }
  u16* ob = outz + (size_t)(b * 129 + t + 1) * 65536;
  ob[j] = f2b(o0);
#pragma unroll
  for (int k = 1; k <= 3; ++k) {
    float m = edge[(size_t)bt * 1024 + k * 256 + j];
    float ok = (t == 0) ? (bgv + m) : (bgv + 0.5f * m + ISQ2 * Atm1 * em1);
    ob[k * 256 + j] = f2b(ok);
  }
}

// ---- G3: y[bt][co][p] = (Wup_kk @ outz_frames^T)*s2 + t2, fp32 out ----
__global__ __launch_bounds__(512, 2) void k_g3(const u16* __restrict__ outz, const u16* __restrict__ Wup,
                                               const float* __restrict__ s2, const float* __restrict__ t2,
                                               float* __restrict__ y) {
  __shared__ u16 sA[32768];
  __shared__ u16 sB[32768];
  int bsw = (int)blockIdx.x;
  int bt = (bsw & 7) * 64 + (bsw >> 3);
  int b = bt >> 7, t = bt & 127;
  int tid = threadIdx.x;
  const u16* Ab = Wup;
  const u16* Bb = outz + (size_t)(b * 129 + t) * 65536;
  f32x4 acc[8][4];
  gemm256_core(Ab, Bb, sA, sB, tid, acc);

  int lane = tid & 63, w = tid >> 6, wr = w >> 2, wc = w & 3;
  int q = lane >> 4, cc16 = lane & 15;
  bool ev = (lane & 1) == 0;
  float* ybase = y + (size_t)bt * 65536;
#pragma unroll
  for (int mi = 0; mi < 8; ++mi) {
    int rl = wr * 128 + mi * 16 + q * 4;
    float4 s4 = *(const float4*)(s2 + rl);
    float4 t4 = *(const float4*)(t2 + rl);
#pragma unroll
    for (int ni = 0; ni < 4; ++ni) {
      float v[4];
      v[0] = acc[mi][ni][0] * s4.x + t4.x;
      v[1] = acc[mi][ni][1] * s4.y + t4.y;
      v[2] = acc[mi][ni][2] * s4.z + t4.z;
      v[3] = acc[mi][ni][3] * s4.w + t4.w;
      store_pairs_f32(ybase, rl, 256, wc * 64 + ni * 16 + (cc16 & ~1), v, ev);
    }
  }
}

extern "C" void kernel_launch(void* const* d_in, const int* in_sizes, int n_in,
                              void* d_out, int out_size, void* d_ws, size_t ws_size,
                              hipStream_t stream) {
  (void)in_sizes; (void)n_in; (void)out_size; (void)ws_size;
  const float* x  = (const float*)d_in[0];
  const float* Wd = (const float*)d_in[2];
  const float* s1 = (const float*)d_in[3];
  const float* t1 = (const float*)d_in[4];
  const float* Wg = (const float*)d_in[5];
  const float* bg = (const float*)d_in[6];
  const float* Wu = (const float*)d_in[7];
  const float* s2 = (const float*)d_in[8];
  const float* t2 = (const float*)d_in[9];
  float* y = (float*)d_out;
  char* ws = (char*)d_ws;
  // padded layout: 517 frames (4*129+1), frames b*129 are shared zero pads
  u16*   outz  = (u16*)(ws);                    // 67,764,224 B
  u16*   xTz   = (u16*)(ws + 67764224);         // 67,764,224 B
  u16*   Wup   = (u16*)(ws + 136052736);        // 384 KiB
  u16*   Wcomb = (u16*)(ws + 136445952);        // 384 KiB
  float* c0    = (float*)(ws + 136839168);      // 1 KiB
  float* tWg   = (float*)(ws + 136840192);      // 1 KiB
  float* edge  = (float*)d_out;                 // scratch in d_out, overwritten by k_g3

  k_pre<<<dim3(10049), dim3(256), 0, stream>>>(x, Wd, Wg, Wu, s1, t1, bg, xTz, outz, Wup, Wcomb, c0, tWg);
  k_g12<<<dim3(512), dim3(512), 0, stream>>>(xTz, Wcomb, c0, tWg, outz, edge);
  k_fix<<<dim3(512), dim3(256), 0, stream>>>(edge, bg, outz);
  k_g3<<<dim3(512), dim3(512), 0, stream>>>(outz, Wup, s2, t2, y);
}

// Round 5
// 403.902 us; speedup vs baseline: 1.1053x; 1.0049x over previous
//
#include <hip/hip_runtime.h>

typedef __attribute__((ext_vector_type(8))) short short8;
typedef __attribute__((ext_vector_type(4))) float f32x4;
typedef unsigned short u16;
typedef unsigned int u32;

#define FENCE() asm volatile("" ::: "memory")

__device__ __forceinline__ void gld_lds16(const void* g, void* l) {
  __builtin_amdgcn_global_load_lds((const __attribute__((address_space(1))) void*)g,
                                   (__attribute__((address_space(3))) void*)l,
                                   16, 0, 0);
}

__device__ __forceinline__ u16 f2b(float x) {
  union { float f; u32 u; } v; v.f = x;
  u32 u = v.u;
  return (u16)((u + 0x7FFFu + ((u >> 16) & 1u)) >> 16);
}
__device__ __forceinline__ float b2f(u16 x) {
  union { u32 u; float f; } v; v.u = ((u32)x) << 16; return v.f;
}
__device__ __forceinline__ u32 pack_pair(float lo, float hi) {
  return (u32)f2b(lo) | ((u32)f2b(hi) << 16);
}

// ==================== merged pre-kernel ====================
// Serial-loop blocks dispatched FIRST (round-4 verified: hides their latency
// under the transpose bulk; 149.6 -> 97.6us).
// blocks [0,768):      Wcomb[kk][j][ci] = sum_co (Wg[co][j]*s1[co]) * Wd[co][ci][kk]
// block  768:          c0/tWg
// blocks [769,1537):   Wup[kk][co][ci] cast
// blocks [1537,1857):  zero pad frames of outz/xTz
// blocks [1857,5953):  transpose+cast x -> xTz, [64 ci]x[128 p] slab per block,
//                      vectorized LDS (b128 write / b64 read + 8x4 reg transpose)
__global__ __launch_bounds__(256) void k_pre(const float* __restrict__ x,
                                             const float* __restrict__ Wd, const float* __restrict__ Wg,
                                             const float* __restrict__ Wu,
                                             const float* __restrict__ s1, const float* __restrict__ t1,
                                             const float* __restrict__ bg,
                                             u16* __restrict__ xTz, u16* __restrict__ outz,
                                             u16* __restrict__ Wup, u16* __restrict__ Wcomb,
                                             float* __restrict__ c0, float* __restrict__ tWg) {
  __shared__ __align__(16) u16 tile[64 * 128];   // 16 KiB, XOR-swizzled columns
  int blk = blockIdx.x;
  int tid = threadIdx.x;
  if (blk < 768) {  // direct Wcomb, 4-way unrolled independent partials
    int kk = blk >> 8;
    int ci = blk & 255;
    int j = tid;
    float a0 = 0.f, a1 = 0.f, a2 = 0.f, a3 = 0.f;
    for (int co = 0; co < 256; co += 4) {
      float w0 = b2f(f2b(Wg[(co + 0) * 256 + j] * s1[co + 0]));
      float w1 = b2f(f2b(Wg[(co + 1) * 256 + j] * s1[co + 1]));
      float w2 = b2f(f2b(Wg[(co + 2) * 256 + j] * s1[co + 2]));
      float w3 = b2f(f2b(Wg[(co + 3) * 256 + j] * s1[co + 3]));
      float d0 = b2f(f2b(Wd[(u32)(co + 0) * 768 + (u32)ci * 3 + kk]));
      float d1 = b2f(f2b(Wd[(u32)(co + 1) * 768 + (u32)ci * 3 + kk]));
      float d2 = b2f(f2b(Wd[(u32)(co + 2) * 768 + (u32)ci * 3 + kk]));
      float d3 = b2f(f2b(Wd[(u32)(co + 3) * 768 + (u32)ci * 3 + kk]));
      a0 = fmaf(w0, d0, a0);
      a1 = fmaf(w1, d1, a1);
      a2 = fmaf(w2, d2, a2);
      a3 = fmaf(w3, d3, a3);
    }
    Wcomb[(size_t)kk * 65536 + (size_t)j * 256 + ci] = f2b((a0 + a1) + (a2 + a3));
    return;
  }
  if (blk == 768) {  // c0[j] = t1 @ Wg[:,j] + bg[j], 4-way unrolled
    int j = tid;
    float a0 = 0.f, a1 = 0.f, a2 = 0.f, a3 = 0.f;
    for (int co = 0; co < 256; co += 4) {
      a0 = fmaf(t1[co + 0], Wg[(co + 0) * 256 + j], a0);
      a1 = fmaf(t1[co + 1], Wg[(co + 1) * 256 + j], a1);
      a2 = fmaf(t1[co + 2], Wg[(co + 2) * 256 + j], a2);
      a3 = fmaf(t1[co + 3], Wg[(co + 3) * 256 + j], a3);
    }
    float a = (a0 + a1) + (a2 + a3);
    tWg[j] = a;
    c0[j] = a + bg[j];
    return;
  }
  if (blk < 1537) {  // Wup cast
    int id = (blk - 769) * 256 + tid;
    int kk = id >> 16;
    int rem = id & 65535;
    int a = rem >> 8, b = rem & 255;
    Wup[id] = f2b(Wu[(u32)a * 768 + (u32)b * 3 + kk]);
    return;
  }
  if (blk < 1857) {  // zero pad frames
    int gid = (blk - 1537) * 256 + tid;
    int i = gid * 8;
    int buf = (i >= 327680) ? 1 : 0;
    int wi = i - buf * 327680;
    int f = wi >> 16;
    int off = wi & 65535;
    u16* dst = (buf ? xTz : outz) + (size_t)f * 129 * 65536 + off;
    *(uint4*)dst = make_uint4(0u, 0u, 0u, 0u);
    return;
  }
  // ---- transpose+cast, vectorized LDS path ----
  int tblk = blk - 1857;
  int tl = tblk >> 3;
  int sub = tblk & 7;
  int ci0 = (sub >> 1) << 6;     // 0 or 64 or 128 or 192
  int p0 = (sub & 1) << 7;       // 0 or 128
  {
    // phase 1: global fp32 -> bf16 -> LDS (b128 writes, swizzled cols)
    int i = tid >> 2;            // ci row 0..63
    int ch = tid & 3;            // p chunk of 32
    const float* gsrc = x + (size_t)tl * 65536 + (ci0 + i) * 256 + p0 + ch * 32;
    __align__(16) u16 cv[32];
#pragma unroll
    for (int v4 = 0; v4 < 8; ++v4) {
      float4 f = *(const float4*)(gsrc + v4 * 4);
      cv[v4 * 4 + 0] = f2b(f.x);
      cv[v4 * 4 + 1] = f2b(f.y);
      cv[v4 * 4 + 2] = f2b(f.z);
      cv[v4 * 4 + 3] = f2b(f.w);
    }
    int swz = ((i & 7) << 4) ^ (((i >> 3) & 1) << 6);
#pragma unroll
    for (int q = 0; q < 4; ++q) {
      int cb = (ch * 64 + q * 16) ^ swz;
      *(uint4*)((char*)tile + i * 256 + cb) = *(const uint4*)&cv[q * 8];
    }
  }
  __syncthreads();
  // phase 2: b64 reads (8 rows x 4 cols), 8x4 register transpose, 16B stores
  int r8 = tid & 7;              // ci octet
  int c32 = tid >> 3;            // p group of 4 (0..31)
  uint2 rows[8];
#pragma unroll
  for (int k = 0; k < 8; ++k) {
    int row = r8 * 8 + k;
    int cb = (c32 * 8) ^ ((row & 7) << 4) ^ (((row >> 3) & 1) << 6);
    rows[k] = *(const uint2*)((const char*)tile + row * 256 + cb);
  }
  int fi = (tl >> 7) * 129 + (tl & 127) + 1;
  u16* gdst0 = xTz + (size_t)fi * 65536 + (size_t)(p0 + c32 * 4) * 256 + ci0 + r8 * 8;
#pragma unroll
  for (int j = 0; j < 4; ++j) {
    u32 e0 = (j < 2) ? rows[0].x : rows[0].y;
    u32 e1 = (j < 2) ? rows[1].x : rows[1].y;
    u32 e2 = (j < 2) ? rows[2].x : rows[2].y;
    u32 e3 = (j < 2) ? rows[3].x : rows[3].y;
    u32 e4 = (j < 2) ? rows[4].x : rows[4].y;
    u32 e5 = (j < 2) ? rows[5].x : rows[5].y;
    u32 e6 = (j < 2) ? rows[6].x : rows[6].y;
    u32 e7 = (j < 2) ? rows[7].x : rows[7].y;
    uint4 o;
    if (j & 1) {
      o.x = (e0 >> 16) | (e1 & 0xFFFF0000u);
      o.y = (e2 >> 16) | (e3 & 0xFFFF0000u);
      o.z = (e4 >> 16) | (e5 & 0xFFFF0000u);
      o.w = (e6 >> 16) | (e7 & 0xFFFF0000u);
    } else {
      o.x = (e0 & 0xFFFFu) | (e1 << 16);
      o.y = (e2 & 0xFFFFu) | (e3 << 16);
      o.z = (e4 & 0xFFFFu) | (e5 << 16);
      o.w = (e6 & 0xFFFFu) | (e7 << 16);
    }
    *(uint4*)(gdst0 + (size_t)j * 256) = o;
  }
}

// ---------------- output store helpers ----------------
__device__ __forceinline__ void store_pairs(u16* base, int row0, int stride, int colb,
                                            const float v[4], bool ev) {
  float pv[4];
#pragma unroll
  for (int r = 0; r < 4; ++r) pv[r] = __shfl_xor(v[r], 1, 64);
  u32 wd0 = ev ? pack_pair(v[0], pv[0]) : pack_pair(pv[0], v[0]);
  u32 wd1 = ev ? pack_pair(v[1], pv[1]) : pack_pair(pv[1], v[1]);
  u32 wd2 = ev ? pack_pair(v[2], pv[2]) : pack_pair(pv[2], v[2]);
  u32 wd3 = ev ? pack_pair(v[3], pv[3]) : pack_pair(pv[3], v[3]);
  u32 wa = ev ? wd0 : wd2;
  u32 wb = ev ? wd1 : wd3;
  int rs = ev ? 0 : 2;
  *(u32*)(base + (size_t)(row0 + rs) * stride + colb) = wa;
  *(u32*)(base + (size_t)(row0 + rs + 1) * stride + colb) = wb;
}

__device__ __forceinline__ void store_pairs_f32(float* base, int row0, int stride, int colb,
                                                const float v[4], bool ev) {
  float pv[4];
#pragma unroll
  for (int r = 0; r < 4; ++r) pv[r] = __shfl_xor(v[r], 1, 64);
  float2 wa, wb;
  if (ev) { wa = make_float2(v[0], pv[0]); wb = make_float2(v[1], pv[1]); }
  else    { wa = make_float2(pv[2], v[2]); wb = make_float2(pv[3], v[3]); }
  int rs = ev ? 0 : 2;
  *(float2*)(base + (size_t)(row0 + rs) * stride + colb) = wa;
  *(float2*)(base + (size_t)(row0 + rs + 1) * stride + colb) = wb;
}

// ================= 256x256 8-phase GEMM core (round-1 verified: 78.9us) =================
// C[256x256] = sum over 12 K-tiles (BK=64) of A[256xK] * B[256xK]^T
// LDS: [dbuf 2][half 2][128 rows][64 k] bf16, XOR-swizzled (byte ^= (row&7)<<4),
// achieved by pre-swizzling the GLOBAL source address (LDS dest stays linear).

__device__ __forceinline__ void stage_part(int s, const u16* Ab, const u16* Bb,
                                           u16* sA, u16* sB, int wuni, int g0) {
  if (s >= 48) return;
  const int tau = s >> 2;
  const int pt = s & 3;              // 0=B0,1=B1,2=A0,3=A1
  const int toff = ((tau >> 2) << 16) + ((tau & 3) << 6);
  const int half = pt & 1;
  const u16* src = ((pt & 2) ? Ab : Bb) + toff + (half << 15) + g0;
  u16* dst = ((pt & 2) ? sA : sB) + ((tau & 1) << 14) + (half << 13) + wuni;
  gld_lds16(src, dst);
  gld_lds16(src + 16384, dst + 4096);
}

template<int QUAD, int NH>
__device__ __forceinline__ void mfma_quad(f32x4 (&acc)[8][4], const short8 (&af)[2][4],
                                          const short8 (&bf)[2][2][2]) {
#pragma unroll
  for (int k = 0; k < 2; ++k)
#pragma unroll
    for (int m = 0; m < 4; ++m)
#pragma unroll
      for (int nj = 0; nj < 2; ++nj)
        acc[QUAD * 4 + m][NH * 2 + nj] = __builtin_amdgcn_mfma_f32_16x16x32_bf16(
            af[k][m], bf[NH][k][nj], acc[QUAD * 4 + m][NH * 2 + nj], 0, 0, 0);
}

__device__ __forceinline__ void gemm256_core(const u16* __restrict__ Ab, const u16* __restrict__ Bb,
                                             u16* sA, u16* sB, int tid, f32x4 (&acc)[8][4]) {
  const int lane = tid & 63;
  const int w = tid >> 6;
  const int wr = w >> 2;        // 0..1
  const int wc = w & 3;         // 0..3
  const int m16 = lane & 15;
  const int xorm = (lane & 7) << 4;       // swizzle mask (bytes)
  const int q16b = (lane >> 4) << 4;      // k-quarter byte offset
  const int koffe0 = ((q16b) ^ xorm) >> 1;        // elems
  const int koffe1 = ((64 + q16b) ^ xorm) >> 1;   // elems
  // staging: thread's global offset (pre-swizzled so linear LDS holds swizzled data)
  const int srow = tid >> 3;                       // 0..63 (j=0)
  const int scol = ((tid & 7) ^ (srow & 7)) << 3;  // 0..56
  const int g0 = srow * 256 + scol;                // j=1 adds 16384
  const int wuni = w << 9;                         // wave-uniform LDS elem base

#pragma unroll
  for (int i = 0; i < 8; ++i)
#pragma unroll
    for (int j = 0; j < 4; ++j) acc[i][j] = (f32x4){0.f, 0.f, 0.f, 0.f};

  // prologue: stage stream parts 0..6 (tile0 all, tile1 B0,B1,A0)
#pragma unroll
  for (int s = 0; s < 7; ++s) stage_part(s, Ab, Bb, sA, sB, wuni, g0);
  asm volatile("s_waitcnt vmcnt(6)" ::: "memory");
  __builtin_amdgcn_s_barrier();
  FENCE();

  short8 af[2][4];
  short8 bf[2][2][2];
#pragma unroll 2
  for (int kt = 0; kt < 12; ++kt) {
    const int cb = kt & 1;
    const u16* aH = sA + cb * 16384 + wr * 8192;
    const u16* bH = sB + cb * 16384 + (wc >> 1) * 8192;
    const int bR0 = (wc & 1) << 6;
    // ---- phase 0: load A-quad0 + all B frags; stage A1(kt+1); MFMA Q(0,0) ----
#pragma unroll
    for (int m = 0; m < 4; ++m) {
      const u16* p = aH + (m * 16 + m16) * 64;
      af[0][m] = *(const short8*)(p + koffe0);
      af[1][m] = *(const short8*)(p + koffe1);
    }
#pragma unroll
    for (int nh = 0; nh < 2; ++nh)
#pragma unroll
      for (int nj = 0; nj < 2; ++nj) {
        const u16* p = bH + (bR0 + (nh * 2 + nj) * 16 + m16) * 64;
        bf[nh][0][nj] = *(const short8*)(p + koffe0);
        bf[nh][1][nj] = *(const short8*)(p + koffe1);
      }
    stage_part(4 * kt + 7, Ab, Bb, sA, sB, wuni, g0);
    FENCE();
    __builtin_amdgcn_s_barrier();
    FENCE();
    __builtin_amdgcn_s_setprio(1);
    mfma_quad<0, 0>(acc, af, bf);
    __builtin_amdgcn_s_setprio(0);
    FENCE();
    __builtin_amdgcn_s_barrier();
    FENCE();
    // ---- phase 1: stage B0(kt+2); MFMA Q(0,1) ----
    stage_part(4 * kt + 8, Ab, Bb, sA, sB, wuni, g0);
    FENCE();
    __builtin_amdgcn_s_barrier();
    FENCE();
    __builtin_amdgcn_s_setprio(1);
    mfma_quad<0, 1>(acc, af, bf);
    __builtin_amdgcn_s_setprio(0);
    FENCE();
    __builtin_amdgcn_s_barrier();
    FENCE();
    // ---- phase 2: reload A-quad1; stage B1(kt+2); MFMA Q(1,0) ----
#pragma unroll
    for (int m = 0; m < 4; ++m) {
      const u16* p = aH + (64 + m * 16 + m16) * 64;
      af[0][m] = *(const short8*)(p + koffe0);
      af[1][m] = *(const short8*)(p + koffe1);
    }
    stage_part(4 * kt + 9, Ab, Bb, sA, sB, wuni, g0);
    FENCE();
    __builtin_amdgcn_s_barrier();
    FENCE();
    __builtin_amdgcn_s_setprio(1);
    mfma_quad<1, 0>(acc, af, bf);
    __builtin_amdgcn_s_setprio(0);
    FENCE();
    __builtin_amdgcn_s_barrier();
    FENCE();
    // ---- phase 3: stage A0(kt+2); MFMA Q(1,1); counted vmcnt ----
    stage_part(4 * kt + 10, Ab, Bb, sA, sB, wuni, g0);
    FENCE();
    __builtin_amdgcn_s_barrier();
    FENCE();
    __builtin_amdgcn_s_setprio(1);
    mfma_quad<1, 1>(acc, af, bf);
    __builtin_amdgcn_s_setprio(0);
    if (kt < 10) asm volatile("s_waitcnt vmcnt(6)" ::: "memory");
    else         asm volatile("s_waitcnt vmcnt(0)" ::: "memory");
    __builtin_amdgcn_s_barrier();
    FENCE();
  }
}

// ---- G12: out_pre[bt][p][j] = sum_kk xTz_frames @ Wcomb_kk^T + c0 ; edge dump p<4 ----
__global__ __launch_bounds__(512, 2) void k_g12(const u16* __restrict__ xTz, const u16* __restrict__ Wcomb,
                                                const float* __restrict__ c0, const float* __restrict__ tWg,
                                                u16* __restrict__ outz, float* __restrict__ edge) {
  __shared__ u16 sA[32768];
  __shared__ u16 sB[32768];
  int bsw = (int)blockIdx.x;
  int bt = (bsw & 7) * 64 + (bsw >> 3);   // XCD swizzle (512 = 8*64)
  int b = bt >> 7, t = bt & 127;
  int tid = threadIdx.x;
  const u16* Ab = xTz + (size_t)(b * 129 + t) * 65536;
  const u16* Bb = Wcomb;
  f32x4 acc[8][4];
  gemm256_core(Ab, Bb, sA, sB, tid, acc);

  int lane = tid & 63, w = tid >> 6, wr = w >> 2, wc = w & 3;
  int q = lane >> 4, cc16 = lane & 15;
  bool ev = (lane & 1) == 0;
  float c0v[4], tWgv[4];
#pragma unroll
  for (int ni = 0; ni < 4; ++ni) {
    int j = wc * 64 + ni * 16 + cc16;
    c0v[ni] = c0[j];
    tWgv[ni] = tWg[j];
  }
  u16* obase = outz + (size_t)(b * 129 + t + 1) * 65536;
#pragma unroll
  for (int mi = 0; mi < 8; ++mi) {
    int row0 = wr * 128 + mi * 16 + q * 4;
#pragma unroll
    for (int ni = 0; ni < 4; ++ni) {
      float v[4];
#pragma unroll
      for (int r = 0; r < 4; ++r) v[r] = acc[mi][ni][r] + c0v[ni];
      store_pairs(obase, row0, 256, wc * 64 + ni * 16 + (cc16 & ~1), v, ev);
    }
  }
  if (wr == 0 && q == 0) {
    float* eb = edge + (size_t)bt * 1024;
#pragma unroll
    for (int ni = 0; ni < 4; ++ni) {
      float vE[4];
#pragma unroll
      for (int r = 0; r < 4; ++r) vE[r] = acc[0][ni][r] + tWgv[ni];
      store_pairs_f32(eb, 0, 256, wc * 64 + ni * 16 + (cc16 & ~1), vE, ev);
    }
  }
}

// ---- fixup: overwrite p<4 nodes with GCN aggregation (closed-form dinv) ----
__device__ __forceinline__ float dinv0(int t) {
  if (t == 0) return 0.44721359549995793f;   // 1/sqrt(5)
  if (t == 127) return 0.7071067811865476f;  // 1/sqrt(2)
  return 0.4082482904638631f;                // 1/sqrt(6)
}
__global__ __launch_bounds__(256) void k_fix(const float* __restrict__ edge, const float* __restrict__ bg,
                                             u16* __restrict__ outz) {
  int bt = blockIdx.x;
  int b = bt >> 7;
  int t = bt & 127;
  int j = threadIdx.x;
  const float ISQ2 = 0.7071067811865476f;
  float bgv = bg[j];
  float e_t = edge[(size_t)bt * 1024 + j];
  float At = dinv0(t);
  float o0 = bgv + At * At * e_t;
  if (t <= 126) {
    float At1 = dinv0(t + 1);
    const float* en = edge + (size_t)(bt + 1) * 1024;
    float s = At1 * en[j] + ISQ2 * (en[256 + j] + en[512 + j] + en[768 + j]);
    o0 += At * s;
  }
  float em1 = 0.f, Atm1 = 0.f;
  if (t >= 1) {
    Atm1 = dinv0(t - 1);
    em1 = edge[(size_t)(bt - 1) * 1024 + j];
    o0 += At * Atm1 * em1;
  }
  u16* ob = outz + (size_t)(b * 129 + t + 1) * 65536;
  ob[j] = f2b(o0);
#pragma unroll
  for (int k = 1; k <= 3; ++k) {
    float m = edge[(size_t)bt * 1024 + k * 256 + j];
    float ok = (t == 0) ? (bgv + m) : (bgv + 0.5f * m + ISQ2 * Atm1 * em1);
    ob[k * 256 + j] = f2b(ok);
  }
}

// ---- G3: y[bt][co][p] = (Wup_kk @ outz_frames^T)*s2 + t2, fp32 out ----
__global__ __launch_bounds__(512, 2) void k_g3(const u16* __restrict__ outz, const u16* __restrict__ Wup,
                                               const float* __restrict__ s2, const float* __restrict__ t2,
                                               float* __restrict__ y) {
  __shared__ u16 sA[32768];
  __shared__ u16 sB[32768];
  int bsw = (int)blockIdx.x;
  int bt = (bsw & 7) * 64 + (bsw >> 3);
  int b = bt >> 7, t = bt & 127;
  int tid = threadIdx.x;
  const u16* Ab = Wup;
  const u16* Bb = outz + (size_t)(b * 129 + t) * 65536;
  f32x4 acc[8][4];
  gemm256_core(Ab, Bb, sA, sB, tid, acc);

  int lane = tid & 63, w = tid >> 6, wr = w >> 2, wc = w & 3;
  int q = lane >> 4, cc16 = lane & 15;
  bool ev = (lane & 1) == 0;
  float* ybase = y + (size_t)bt * 65536;
#pragma unroll
  for (int mi = 0; mi < 8; ++mi) {
    int rl = wr * 128 + mi * 16 + q * 4;
    float4 s4 = *(const float4*)(s2 + rl);
    float4 t4 = *(const float4*)(t2 + rl);
#pragma unroll
    for (int ni = 0; ni < 4; ++ni) {
      float v[4];
      v[0] = acc[mi][ni][0] * s4.x + t4.x;
      v[1] = acc[mi][ni][1] * s4.y + t4.y;
      v[2] = acc[mi][ni][2] * s4.z + t4.z;
      v[3] = acc[mi][ni][3] * s4.w + t4.w;
      store_pairs_f32(ybase, rl, 256, wc * 64 + ni * 16 + (cc16 & ~1), v, ev);
    }
  }
}

extern "C" void kernel_launch(void* const* d_in, const int* in_sizes, int n_in,
                              void* d_out, int out_size, void* d_ws, size_t ws_size,
                              hipStream_t stream) {
  (void)in_sizes; (void)n_in; (void)out_size; (void)ws_size;
  const float* x  = (const float*)d_in[0];
  const float* Wd = (const float*)d_in[2];
  const float* s1 = (const float*)d_in[3];
  const float* t1 = (const float*)d_in[4];
  const float* Wg = (const float*)d_in[5];
  const float* bg = (const float*)d_in[6];
  const float* Wu = (const float*)d_in[7];
  const float* s2 = (const float*)d_in[8];
  const float* t2 = (const float*)d_in[9];
  float* y = (float*)d_out;
  char* ws = (char*)d_ws;
  // padded layout: 517 frames (4*129+1), frames b*129 are shared zero pads
  u16*   outz  = (u16*)(ws);                    // 67,764,224 B
  u16*   xTz   = (u16*)(ws + 67764224);         // 67,764,224 B
  u16*   Wup   = (u16*)(ws + 136052736);        // 384 KiB
  u16*   Wcomb = (u16*)(ws + 136445952);        // 384 KiB
  float* c0    = (float*)(ws + 136839168);      // 1 KiB
  float* tWg   = (float*)(ws + 136840192);      // 1 KiB
  float* edge  = (float*)d_out;                 // scratch in d_out, overwritten by k_g3

  k_pre<<<dim3(5953), dim3(256), 0, stream>>>(x, Wd, Wg, Wu, s1, t1, bg, xTz, outz, Wup, Wcomb, c0, tWg);
  k_g12<<<dim3(512), dim3(512), 0, stream>>>(xTz, Wcomb, c0, tWg, outz, edge);
  k_fix<<<dim3(512), dim3(256), 0, stream>>>(edge, bg, outz);
  k_g3<<<dim3(512), dim3(512), 0, stream>>>(outz, Wup, s2, t2, y);
}